// Round 7
// baseline (726.019 us; speedup 1.0000x reference)
//
#include <hip/hip_runtime.h>
#include <hip/hip_bf16.h>

#define NN 50000
#define NE 800000

typedef unsigned short u16;
typedef unsigned int   u32;
typedef unsigned char  u8;

typedef __attribute__((ext_vector_type(8))) __bf16 bf16x8;
typedef __attribute__((ext_vector_type(4))) float  f32x4;

__device__ __forceinline__ float bf2f(u16 x) {
    u32 u = ((u32)x) << 16;
    return __builtin_bit_cast(float, u);
}
__device__ __forceinline__ u16 f2bf(float f) {
    u32 u = __builtin_bit_cast(u32, f);
    u32 r = (u + 0x7FFFu + ((u >> 16) & 1u)) >> 16;
    return (u16)r;
}
__device__ __forceinline__ float bflo(u32 w) { return __builtin_bit_cast(float, w << 16); }
__device__ __forceinline__ float bfhi(u32 w) { return __builtin_bit_cast(float, w & 0xffff0000u); }

// BN+ReLU on 2 packed bf16 with per-element scale/shift
__device__ __forceinline__ u32 bnpack2(u32 w, float sc0, float sc1, float sh0, float sh1) {
    float x0 = fmaxf(fmaf(bflo(w), sc0, sh0), 0.f);
    float x1 = fmaxf(fmaf(bfhi(w), sc1, sh1), 0.f);
    return (u32)f2bf(x0) | ((u32)f2bf(x1) << 16);
}
__device__ __forceinline__ uint4 bnpack8(uint4 a, float4 sa, float4 sb, float4 ha, float4 hb) {
    uint4 o;
    o.x = bnpack2(a.x, sa.x, sa.y, ha.x, ha.y);
    o.y = bnpack2(a.y, sa.z, sa.w, ha.z, ha.w);
    o.z = bnpack2(a.z, sb.x, sb.y, hb.x, hb.y);
    o.w = bnpack2(a.w, sb.z, sb.w, hb.z, hb.w);
    return o;
}

// ---------------- graph preprocessing ----------------

__global__ __launch_bounds__(256) void count_k(const int* __restrict__ dst, int* __restrict__ deg, int E) {
    int e = blockIdx.x * 256 + threadIdx.x;
    if (e < E) atomicAdd(&deg[dst[e]], 1);
}

__global__ __launch_bounds__(256) void dinv_k(const int* __restrict__ deg, float* __restrict__ dinv, int n) {
    int i = blockIdx.x * 256 + threadIdx.x;
    if (i < n) dinv[i] = rsqrtf((float)deg[i] + 1.0f);
}

__global__ __launch_bounds__(256) void scan1_k(const int* __restrict__ deg, int* __restrict__ bsum, int n) {
    __shared__ int sd[256];
    int i = blockIdx.x * 256 + threadIdx.x;
    sd[threadIdx.x] = (i < n) ? deg[i] : 0;
    __syncthreads();
    for (int s = 128; s > 0; s >>= 1) {
        if (threadIdx.x < s) sd[threadIdx.x] += sd[threadIdx.x + s];
        __syncthreads();
    }
    if (threadIdx.x == 0) bsum[blockIdx.x] = sd[0];
}

__global__ __launch_bounds__(256) void scan2_k(int* __restrict__ bsum, int nb) {
    __shared__ int sd[256];
    int t = threadIdx.x;
    int v = (t < nb) ? bsum[t] : 0;
    sd[t] = v;
    __syncthreads();
    for (int off = 1; off < 256; off <<= 1) {
        int tv = (t >= off) ? sd[t - off] : 0;
        __syncthreads();
        sd[t] += tv;
        __syncthreads();
    }
    if (t < nb) bsum[t] = sd[t] - v;  // exclusive
}

__global__ __launch_bounds__(256) void scan3_k(const int* __restrict__ deg, const int* __restrict__ bofs,
                                               int* __restrict__ rs, int* __restrict__ cur, int n) {
    __shared__ int sd[256];
    int t = threadIdx.x;
    int i = blockIdx.x * 256 + t;
    int v = (i < n) ? deg[i] : 0;
    sd[t] = v;
    __syncthreads();
    for (int off = 1; off < 256; off <<= 1) {
        int tv = (t >= off) ? sd[t - off] : 0;
        __syncthreads();
        sd[t] += tv;
        __syncthreads();
    }
    int excl = sd[t] - v + bofs[blockIdx.x];
    if (i < n) { rs[i] = excl; cur[i] = excl; }
}

__global__ __launch_bounds__(256) void fill_k(const int* __restrict__ src, const int* __restrict__ dst,
                                              int* __restrict__ cur, int* __restrict__ csr, int E) {
    int e = blockIdx.x * 256 + threadIdx.x;
    if (e < E) {
        int d = dst[e];
        int pos = atomicAdd(&cur[d], 1);
        csr[pos] = src[e];
    }
}

// ---------------- x f32 -> bf16 cast ----------------

__global__ __launch_bounds__(256) void cast_k(const float* __restrict__ X, u16* __restrict__ Y, int total) {
    int idx = (blockIdx.x * 256 + threadIdx.x) * 8;
    if (idx >= total) return;
    float4 a = *(const float4*)(X + idx);
    float4 b = *(const float4*)(X + idx + 4);
    uint4 o;
    o.x = (u32)f2bf(a.x) | ((u32)f2bf(a.y) << 16);
    o.y = (u32)f2bf(a.z) | ((u32)f2bf(a.w) << 16);
    o.z = (u32)f2bf(b.x) | ((u32)f2bf(b.y) << 16);
    o.w = (u32)f2bf(b.z) | ((u32)f2bf(b.w) << 16);
    *(uint4*)(Y + idx) = o;
}

// ---------------- weight transpose+cast: W f32[K][F] -> Wt bf16[F][K] ----------------

__global__ __launch_bounds__(256) void transpose_k(const float* __restrict__ W, u16* __restrict__ Wt, int K, int F) {
    __shared__ float t[32][33];
    int k0 = blockIdx.x * 32, f0 = blockIdx.y * 32;
    int tx = threadIdx.x & 31, ty = threadIdx.x >> 5;
    for (int r = ty; r < 32; r += 8) t[r][tx] = W[(size_t)(k0 + r) * F + f0 + tx];
    __syncthreads();
    for (int r = ty; r < 32; r += 8) Wt[(size_t)(f0 + r) * K + k0 + tx] = f2bf(t[tx][r]);
}

// ---------------- unified GCN aggregation (pull, CSR by dst) ----------------
// Block = 4 waves; wave w handles edges jj ≡ w (mod 4); each wave's 64 lanes span the
// full F-wide row. LDS merge at end.
// MODE 0: plain gather, bf16 out.                         (agg1)
// MODE 1: BN+ReLU applied per gathered value, bf16 out.   (agg2)
// MODE 2: plain gather + b3 + xres, f32 out.              (agg3)
// TBL 0: bf16 table.  TBL 1: fp8-e4m3 table (F must be 512).

template <int F, int MODE, int TBL>
__global__ __launch_bounds__(256) void aggu_k(const void* __restrict__ Xv, u16* __restrict__ Y,
                                              float* __restrict__ Yf,
                                              const float* __restrict__ dinv, const int* __restrict__ rs,
                                              const int* __restrict__ dg, const int* __restrict__ csr,
                                              const float* __restrict__ scale, const float* __restrict__ shift,
                                              const float* __restrict__ b3, const float* __restrict__ xres) {
    constexpr int FB = F / 64;  // feats per lane (4 or 8)
    const int i = blockIdx.x;
    const int tid = threadIdx.x;
    const int sl = tid >> 6;      // wave/slice 0..3
    const int lane = tid & 63;
    const int start = rs[i], cnt = dg[i];
    const float di = dinv[i];

    __shared__ int   s_idx[64];
    __shared__ float s_w[64];
    __shared__ float red[4][F];

    float sc[FB], sh[FB];
    if constexpr (MODE == 1) {
        #pragma unroll
        for (int k = 0; k < FB; k++) {
            sc[k] = scale[lane * FB + k];
            sh[k] = shift[lane * FB + k];
        }
    }

    float acc[FB];
    #pragma unroll
    for (int k = 0; k < FB; k++) acc[k] = 0.f;

    auto gadd = [&](int row, float wgt) {
        float v[FB];
        if constexpr (TBL == 1) {
            const u8* X8 = (const u8*)Xv;
            uint2 p = *(const uint2*)(X8 + (size_t)row * F + lane * 8);
            v[0] = __builtin_amdgcn_cvt_f32_fp8(p.x, 0);
            v[1] = __builtin_amdgcn_cvt_f32_fp8(p.x, 1);
            v[2] = __builtin_amdgcn_cvt_f32_fp8(p.x, 2);
            v[3] = __builtin_amdgcn_cvt_f32_fp8(p.x, 3);
            v[4] = __builtin_amdgcn_cvt_f32_fp8(p.y, 0);
            v[5] = __builtin_amdgcn_cvt_f32_fp8(p.y, 1);
            v[6] = __builtin_amdgcn_cvt_f32_fp8(p.y, 2);
            v[7] = __builtin_amdgcn_cvt_f32_fp8(p.y, 3);
        } else if constexpr (FB == 4) {
            const u16* X = (const u16*)Xv;
            uint2 p = *(const uint2*)(X + (size_t)row * F + lane * 4);
            v[0] = bflo(p.x); v[1] = bfhi(p.x);
            v[2] = bflo(p.y); v[3] = bfhi(p.y);
        } else {
            const u16* X = (const u16*)Xv;
            uint4 p = *(const uint4*)(X + (size_t)row * F + lane * 8);
            v[0] = bflo(p.x); v[1] = bfhi(p.x);
            v[2] = bflo(p.y); v[3] = bfhi(p.y);
            v[4] = bflo(p.z); v[5] = bfhi(p.z);
            v[6] = bflo(p.w); v[7] = bfhi(p.w);
        }
        #pragma unroll
        for (int k = 0; k < FB; k++) {
            if constexpr (MODE == 1) v[k] = fmaxf(fmaf(v[k], sc[k], sh[k]), 0.f);
            acc[k] = fmaf(v[k], wgt, acc[k]);
        }
    };

    if (sl == 0) gadd(i, di);  // self-loop term

    for (int base = 0; base < cnt; base += 64) {
        const int m = min(64, cnt - base);
        __syncthreads();
        if (tid < m) {
            int s = csr[start + base + tid];
            s_idx[tid] = s;
            s_w[tid] = dinv[s];
        }
        __syncthreads();
        #pragma unroll 2
        for (int jj = sl; jj < m; jj += 4)
            gadd(s_idx[jj], s_w[jj]);
    }

    #pragma unroll
    for (int k = 0; k < FB; k++) red[sl][lane * FB + k] = acc[k];
    __syncthreads();

    if constexpr (MODE == 2) {
        const int f = tid;  // F == 256
        float v = red[0][f] + red[1][f] + red[2][f] + red[3][f];
        Yf[(size_t)i * 256 + f] = v * di + b3[f] + xres[(size_t)i * 256 + f];
    } else {
        if (tid < F / 2) {
            const int f0 = tid * 2;
            float v0 = (red[0][f0] + red[1][f0] + red[2][f0] + red[3][f0]) * di;
            float v1 = (red[0][f0 + 1] + red[1][f0 + 1] + red[2][f0 + 1] + red[3][f0 + 1]) * di;
            *(u32*)(Y + (size_t)i * F + f0) = (u32)f2bf(v0) | ((u32)f2bf(v1) << 16);
        }
    }
}

// ---------------- bf16 MFMA GEMM: C[M][F] = A[M][K] @ Wt[F][K]^T ----------------
// 128x128 tile, BK=32, 4 waves each 64x64 (4x4 of 16x16x32 MFMA).
// STATS: fused per-column sum/sumsq atomics.  BIAS: +bias[col].
// CFP8: write C as fp8-e4m3 (1B/elem).  ABN: apply scale/shift+ReLU to A during staging.

template <bool STATS, bool BIAS, bool CFP8, bool ABN>
__global__ __launch_bounds__(256) void gemm_k(const u16* __restrict__ A, const u16* __restrict__ Wt,
                                              const float* __restrict__ bias, void* __restrict__ C,
                                              float* __restrict__ colsum, float* __restrict__ colsq,
                                              const float* __restrict__ ascale, const float* __restrict__ ashift,
                                              int M, int K, int F) {
    __shared__ u16 As[128 * 40];
    __shared__ u16 Bs[128 * 40];
    const int m0 = blockIdx.x * 128, f0 = blockIdx.y * 128;
    const int tid = threadIdx.x;
    const int lane = tid & 63, wave = tid >> 6;
    const int waveM = (wave >> 1) * 64, waveN = (wave & 1) * 64;
    const int lrow = tid >> 2, lch = tid & 3;

    f32x4 acc[4][4];
    const f32x4 fz = {0.f, 0.f, 0.f, 0.f};
    #pragma unroll
    for (int i = 0; i < 4; i++)
        #pragma unroll
        for (int j = 0; j < 4; j++) acc[i][j] = fz;

    const int rA0 = m0 + lrow, rA1 = m0 + 64 + lrow;
    const u16* pA0 = A + (size_t)rA0 * K + lch * 8;
    const u16* pA1 = A + (size_t)rA1 * K + lch * 8;
    const u16* pB0 = Wt + (size_t)(f0 + lrow) * K + lch * 8;
    const u16* pB1 = Wt + (size_t)(f0 + 64 + lrow) * K + lch * 8;
    u16* qA0 = &As[lrow * 40 + lch * 8];
    u16* qA1 = &As[(64 + lrow) * 40 + lch * 8];
    u16* qB0 = &Bs[lrow * 40 + lch * 8];
    u16* qB1 = &Bs[(64 + lrow) * 40 + lch * 8];
    const uint4 z4 = {0u, 0u, 0u, 0u};

    const int fm = lane & 15, fq = lane >> 4;

    for (int k0 = 0; k0 < K; k0 += 32) {
        uint4 a0 = (rA0 < M) ? *(const uint4*)(pA0 + k0) : z4;
        uint4 a1 = (rA1 < M) ? *(const uint4*)(pA1 + k0) : z4;
        uint4 b0 = *(const uint4*)(pB0 + k0);
        uint4 b1 = *(const uint4*)(pB1 + k0);
        if constexpr (ABN) {
            const float4 sa = *(const float4*)(ascale + k0 + lch * 8);
            const float4 sb = *(const float4*)(ascale + k0 + lch * 8 + 4);
            const float4 ha = *(const float4*)(ashift + k0 + lch * 8);
            const float4 hb = *(const float4*)(ashift + k0 + lch * 8 + 4);
            a0 = bnpack8(a0, sa, sb, ha, hb);
            a1 = bnpack8(a1, sa, sb, ha, hb);
        }
        __syncthreads();
        *(uint4*)qA0 = a0;
        *(uint4*)qA1 = a1;
        *(uint4*)qB0 = b0;
        *(uint4*)qB1 = b1;
        __syncthreads();
        bf16x8 af[4], bfr[4];
        #pragma unroll
        for (int i = 0; i < 4; i++)
            af[i] = *(const bf16x8*)&As[(waveM + i * 16 + fm) * 40 + fq * 8];
        #pragma unroll
        for (int j = 0; j < 4; j++)
            bfr[j] = *(const bf16x8*)&Bs[(waveN + j * 16 + fm) * 40 + fq * 8];
        #pragma unroll
        for (int i = 0; i < 4; i++)
            #pragma unroll
            for (int j = 0; j < 4; j++)
                acc[i][j] = __builtin_amdgcn_mfma_f32_16x16x32_bf16(af[i], bfr[j], acc[i][j], 0, 0, 0);
    }

    // C/D layout: col=lane&15, row=(lane>>4)*4+reg  [learn_hip m89/m91]
    #pragma unroll
    for (int j = 0; j < 4; j++) {
        const int col = f0 + waveN + j * 16 + fm;
        const float bcol = BIAS ? bias[col] : 0.f;
        float s = 0.f, s2 = 0.f;
        #pragma unroll
        for (int i = 0; i < 4; i++) {
            const int rb = m0 + waveM + i * 16 + fq * 4;
            #pragma unroll
            for (int r = 0; r < 4; r++) {
                const int row = rb + r;
                if (row < M) {
                    float v = acc[i][j][r] + bcol;
                    if constexpr (CFP8) {
                        u32 q = __builtin_amdgcn_cvt_pk_fp8_f32(v, v, 0u, false);
                        ((u8*)C)[(size_t)row * F + col] = (u8)(q & 0xffu);
                    } else {
                        ((u16*)C)[(size_t)row * F + col] = f2bf(v);
                    }
                    if (STATS) { s += v; s2 += v * v; }
                }
            }
        }
        if (STATS) {
            s += __shfl_xor(s, 16);
            s += __shfl_xor(s, 32);
            s2 += __shfl_xor(s2, 16);
            s2 += __shfl_xor(s2, 32);
            if (fq == 0) {
                atomicAdd(&colsum[col], s);
                atomicAdd(&colsq[col], s2);
            }
        }
    }
}

// ---------------- BN finalize ----------------

__global__ __launch_bounds__(256) void bnfin_k(const float* __restrict__ sum, const float* __restrict__ sq,
                                               const float* __restrict__ g, const float* __restrict__ be,
                                               float* __restrict__ scale, float* __restrict__ shift,
                                               int F, float invN) {
    int f = blockIdx.x * 256 + threadIdx.x;
    if (f < F) {
        float m = sum[f] * invN;
        float v = sq[f] * invN - m * m;
        float s = rsqrtf(v + 1e-5f) * g[f];
        scale[f] = s;
        shift[f] = be[f] - m * s;
    }
}

// ---------------- launch ----------------

extern "C" void kernel_launch(void* const* d_in, const int* in_sizes, int n_in,
                              void* d_out, int out_size, void* d_ws, size_t ws_size,
                              hipStream_t stream) {
    const float* x   = (const float*)d_in[0];
    const int*   ei  = (const int*)d_in[1];
    const float* W1  = (const float*)d_in[2];
    const float* b1  = (const float*)d_in[3];
    const float* pg1 = (const float*)d_in[4];
    const float* pbe1= (const float*)d_in[5];
    const float* W2  = (const float*)d_in[6];
    const float* b2  = (const float*)d_in[7];
    const float* pg2 = (const float*)d_in[8];
    const float* pbe2= (const float*)d_in[9];
    const float* W3  = (const float*)d_in[10];
    const float* b3  = (const float*)d_in[11];
    float* out = (float*)d_out;

    char* ws = (char*)d_ws;
    size_t off = 0;
    auto alloc = [&](size_t bytes) -> char* {
        char* p = ws + off;
        off += (bytes + 255) & ~(size_t)255;
        return p;
    };
    float* dinv  = (float*)alloc(NN * 4);
    int*   deg   = (int*)alloc(NN * 4);
    int*   rs    = (int*)alloc(NN * 4);
    int*   cur   = (int*)alloc(NN * 4);
    int*   bsum  = (int*)alloc(256 * 4);
    int*   csr   = (int*)alloc(NE * 4);
    float* stats = (float*)alloc(4 * 512 * 4);
    float* cs1 = stats, *cq1 = stats + 512, *cs2 = stats + 1024, *cq2 = stats + 1536;
    float* scale1 = (float*)alloc(512 * 4);
    float* shift1 = (float*)alloc(512 * 4);
    float* scale2 = (float*)alloc(512 * 4);
    float* shift2 = (float*)alloc(512 * 4);
    u16*   W1t   = (u16*)alloc((size_t)512 * 256 * 2);
    u16*   W2t   = (u16*)alloc((size_t)512 * 512 * 2);
    u16*   W3t   = (u16*)alloc((size_t)256 * 512 * 2);
    u16*   REG   = (u16*)alloc((size_t)NN * 512 * 2);   // 51.2 MB shared region
    u16*   G3    = (u16*)alloc((size_t)NN * 256 * 2);   // 25.6 MB; doubles as XB

    u8*  HB1 = (u8*)REG;     // fp8 H1 [N,512] = 25.6 MB (first half of REG)
    u16* H2  = REG;          // bf16 H2 [N,512] = 51.2 MB (all of REG; HB1 dead by then)
    u16* XB  = G3;           // bf16 x — dead before gemm3 writes G3
    u16* A1  = (u16*)d_out;  // bf16 scratch [N,256]
    u16* A2  = (u16*)d_out;  // bf16 scratch [N,512]

    const int* srcp = ei;
    const int* dstp = ei + NE;

    hipMemsetAsync(deg, 0, NN * 4, stream);
    hipMemsetAsync(stats, 0, 4 * 512 * 4, stream);

    const int nbN = (NN + 255) / 256;
    count_k<<<(NE + 255) / 256, 256, 0, stream>>>(dstp, deg, NE);
    dinv_k<<<nbN, 256, 0, stream>>>(deg, dinv, NN);
    scan1_k<<<nbN, 256, 0, stream>>>(deg, bsum, NN);
    scan2_k<<<1, 256, 0, stream>>>(bsum, nbN);
    scan3_k<<<nbN, 256, 0, stream>>>(deg, bsum, rs, cur, NN);
    fill_k<<<(NE + 255) / 256, 256, 0, stream>>>(srcp, dstp, cur, csr, NE);

    transpose_k<<<dim3(256 / 32, 512 / 32), 256, 0, stream>>>(W1, W1t, 256, 512);
    transpose_k<<<dim3(512 / 32, 512 / 32), 256, 0, stream>>>(W2, W2t, 512, 512);
    transpose_k<<<dim3(512 / 32, 256 / 32), 256, 0, stream>>>(W3, W3t, 512, 256);

    cast_k<<<NN * 256 / 8 / 256, 256, 0, stream>>>(x, XB, NN * 256);

    const int MT = (NN + 127) / 128;  // 391

    // Layer 1: A1 = Agg(XB); H1 = A1@W1 + b1 -> HB1 [fp8] + stats
    aggu_k<256, 0, 0><<<NN, 256, 0, stream>>>(XB, A1, nullptr, dinv, rs, deg, csr,
                                              nullptr, nullptr, nullptr, nullptr);
    gemm_k<true, true, true, false><<<dim3(MT, 4), 256, 0, stream>>>(
        A1, W1t, b1, HB1, cs1, cq1, nullptr, nullptr, NN, 256, 512);
    bnfin_k<<<2, 256, 0, stream>>>(cs1, cq1, pg1, pbe1, scale1, shift1, 512, 1.f / NN);

    // Layer 2: A2 = Agg(relu(bn(H1))) from fp8 table; H2 = A2@W2 + b2 -> H2 [bf16] + stats
    aggu_k<512, 1, 1><<<NN, 256, 0, stream>>>(HB1, A2, nullptr, dinv, rs, deg, csr,
                                              scale1, shift1, nullptr, nullptr);
    gemm_k<true, true, false, false><<<dim3(MT, 4), 256, 0, stream>>>(
        A2, W2t, b2, H2, cs2, cq2, nullptr, nullptr, NN, 512, 512);
    bnfin_k<<<2, 256, 0, stream>>>(cs2, cq2, pg2, pbe2, scale2, shift2, 512, 1.f / NN);

    // Layer 3: G3 = relu(bn(H2))@W3 (BN fused into A staging); out = Agg(G3) + b3 + x
    gemm_k<false, false, false, true><<<dim3(MT, 2), 256, 0, stream>>>(
        H2, W3t, nullptr, G3, nullptr, nullptr, scale2, shift2, NN, 512, 256);
    aggu_k<256, 2, 0><<<NN, 256, 0, stream>>>(G3, nullptr, out, dinv, rs, deg, csr,
                                              nullptr, nullptr, b3, x);
}